// Round 1
// baseline (80.880 us; speedup 1.0000x reference)
//
#include <hip/hip_runtime.h>
#include <hip/hip_bf16.h>

#define B_N   8192
#define DIN   512
#define DH    512
#define NACT  18
#define NTASK 16
#define BM    64
#define BK    32
#define BNB   256   // N columns per block in gemm1
#define MAXTILE 160

typedef __attribute__((ext_vector_type(8))) short  short8v;
typedef __attribute__((ext_vector_type(8))) unsigned short ushort8v;
typedef __attribute__((ext_vector_type(4))) float  float4v;
typedef __attribute__((ext_vector_type(4))) unsigned short ushort4v;

__device__ __forceinline__ unsigned short f2bf(float f) {
  union { float f; unsigned int u; } c; c.f = f;
  unsigned int u = c.u;
  u += 0x7fffu + ((u >> 16) & 1u);   // RNE
  return (unsigned short)(u >> 16);
}
__device__ __forceinline__ float bf2f(unsigned short u) {
  union { unsigned int u; float f; } c; c.u = ((unsigned int)u) << 16;
  return c.f;
}

// ---------------------------------------------------------------- histogram
__global__ __launch_bounds__(1024) void k_hist(
    const int* __restrict__ task_id,
    int* __restrict__ cnt, int* __restrict__ off,
    int* __restrict__ tl_task, int* __restrict__ tl_row0, int* __restrict__ tl_cnt,
    int* __restrict__ ntile, int* __restrict__ rowidx) {
  __shared__ int s_cnt[NTASK];
  __shared__ int s_off[NTASK];
  __shared__ int s_cur[NTASK];
  int tid = threadIdx.x;
  if (tid < NTASK) s_cnt[tid] = 0;
  __syncthreads();
  for (int i = tid; i < B_N; i += 1024) atomicAdd(&s_cnt[task_id[i]], 1);
  __syncthreads();
  if (tid == 0) {
    int acc = 0, nt = 0;
    for (int t = 0; t < NTASK; ++t) {
      s_off[t] = acc;
      int c = s_cnt[t];
      for (int r = 0; r < c; r += BM) {
        tl_task[nt] = t; tl_row0[nt] = acc + r;
        tl_cnt[nt] = (c - r < BM) ? (c - r) : BM;
        ++nt;
      }
      acc += c;
    }
    *ntile = nt;
  }
  __syncthreads();
  if (tid < NTASK) { s_cur[tid] = s_off[tid]; cnt[tid] = s_cnt[tid]; off[tid] = s_off[tid]; }
  __syncthreads();
  for (int i = tid; i < B_N; i += 1024) {
    int t = task_id[i];
    int pos = atomicAdd(&s_cur[t], 1);
    rowidx[pos] = i;
  }
}

// --------------------------------------------- W1 [t][k][n] f32 -> W1T [t][n][k] bf16
__global__ __launch_bounds__(256) void k_tw1(const float* __restrict__ W1,
                                             short* __restrict__ W1T) {
  int nb = blockIdx.x, kb = blockIdx.y, t = blockIdx.z;
  __shared__ float lds[32][33];
  int tid = threadIdx.x;
  int r  = tid >> 3;          // 0..31
  int c4 = (tid & 7) << 2;    // 0,4,...,28
  const float* src = W1 + ((size_t)t * DIN + (size_t)(kb * 32 + r)) * DH + nb * 32 + c4;
  float4v v = *(const float4v*)src;
#pragma unroll
  for (int i = 0; i < 4; ++i) lds[c4 + i][r] = v[i];   // lds[n_local][k_local]
  __syncthreads();
  int nr = nb * 32 + r;
  int kc = kb * 32 + c4;
  ushort4v o;
#pragma unroll
  for (int i = 0; i < 4; ++i) o[i] = f2bf(lds[r][c4 + i]);
  *(ushort4v*)(W1T + ((size_t)t * DH + nr) * DIN + kc) = o;
}

// --------------------------------------------- W2 [t][k][j] f32 -> W2T [t][j][k] f32
__global__ __launch_bounds__(256) void k_tw2(const float* __restrict__ W2,
                                             float* __restrict__ W2T) {
  int t = blockIdx.x;
  __shared__ float lds[DIN * NACT];   // 36 KB
  for (int i = threadIdx.x; i < DIN * NACT; i += 256)
    lds[i] = W2[(size_t)t * DIN * NACT + i];
  __syncthreads();
  for (int o = threadIdx.x; o < DIN * NACT; o += 256) {
    int j = o >> 9, k = o & 511;
    W2T[(size_t)t * NACT * DIN + o] = lds[k * NACT + j];
  }
}

// ---------------------------------------------------------------- grouped GEMM1
// h[row] = relu(x[row] @ W1[task] + b1[task]); scatter to original row order (bf16)
__global__ __launch_bounds__(256) void k_gemm1(
    const float* __restrict__ x, const float* __restrict__ b1,
    const short* __restrict__ W1T, const int* __restrict__ rowidx,
    const int* __restrict__ tl_task, const int* __restrict__ tl_row0,
    const int* __restrict__ tl_cnt, const int* __restrict__ ntile,
    short* __restrict__ hbuf) {
  __shared__ __align__(16) short sA[BM][BK + 8];    // 64 x 40 bf16
  __shared__ __align__(16) short sB[BNB][BK + 8];   // 256 x 40 bf16
  __shared__ int s_rows[BM];
  int nt = *ntile;
  int tid  = threadIdx.x;
  int lane = tid & 63, wave = tid >> 6;
  int nhalf  = blockIdx.x & 1;          // which 256-col half
  int n0base = nhalf * BNB;
  int stride = gridDim.x >> 1;

  for (int ti = (blockIdx.x >> 1); ti < nt; ti += stride) {
    int task = tl_task[ti], row0 = tl_row0[ti], mcnt = tl_cnt[ti];
    __syncthreads();   // previous iter done with s_rows / LDS
    if (tid < BM) {
      int rr = tid < mcnt ? tid : (mcnt - 1);
      s_rows[tid] = rowidx[row0 + rr];
    }
    __syncthreads();

    float4v acc[4][4];
#pragma unroll
    for (int m = 0; m < 4; ++m)
#pragma unroll
      for (int n = 0; n < 4; ++n) acc[m][n] = (float4v)0.0f;

    const short* w1 = W1T + ((size_t)task * DH + n0base) * DIN;

    for (int k0 = 0; k0 < DIN; k0 += BK) {
      // stage A: 64 rows x 32 k, f32 -> bf16
      {
        int r  = tid >> 2;            // 0..63
        int kc = (tid & 3) << 3;      // 0,8,16,24
        const float* src = x + (size_t)s_rows[r] * DIN + k0 + kc;
        float4v v0 = *(const float4v*)src;
        float4v v1 = *(const float4v*)(src + 4);
        ushort8v pk;
#pragma unroll
        for (int i = 0; i < 4; ++i) { pk[i] = f2bf(v0[i]); pk[4 + i] = f2bf(v1[i]); }
        *(ushort8v*)&sA[r][kc] = pk;
      }
      // stage B: 256 n-rows x 32 k bf16 (already transposed)
      for (int j = tid; j < BNB * 4; j += 256) {
        int r  = j >> 2;
        int kc = (j & 3) << 3;
        *(ushort8v*)&sB[r][kc] =
            *(const ushort8v*)(w1 + (size_t)r * DIN + k0 + kc);
      }
      __syncthreads();

      int klo = (lane >> 4) << 3;   // 0 or 8..24
      int rlo = lane & 15;
      short8v a[4];
#pragma unroll
      for (int m = 0; m < 4; ++m) a[m] = *(short8v*)&sA[m * 16 + rlo][klo];
#pragma unroll
      for (int n = 0; n < 4; ++n) {
        short8v b = *(short8v*)&sB[wave * 64 + n * 16 + rlo][klo];
#pragma unroll
        for (int m = 0; m < 4; ++m)
          acc[m][n] = __builtin_amdgcn_mfma_f32_16x16x32_bf16(a[m], b, acc[m][n], 0, 0, 0);
      }
      __syncthreads();
    }

    // epilogue: +b1, relu, cast bf16, scatter to original rows
    int rbase = (lane >> 4) << 2;
    int cl = lane & 15;
#pragma unroll
    for (int n = 0; n < 4; ++n) {
      int col = n0base + wave * 64 + n * 16 + cl;
      float bias = b1[task * DH + col];
#pragma unroll
      for (int m = 0; m < 4; ++m) {
#pragma unroll
        for (int r = 0; r < 4; ++r) {
          int mr = m * 16 + rbase + r;
          if (mr < mcnt) {
            float v = acc[m][n][r] + bias;
            v = fmaxf(v, 0.0f);
            hbuf[(size_t)s_rows[mr] * DH + col] = (short)f2bf(v);
          }
        }
      }
    }
  }
}

// ---------------------------------------------------------------- head: layer2 + log_softmax
__global__ __launch_bounds__(256) void k_head(
    const short* __restrict__ hbuf, const float* __restrict__ W2T,
    const float* __restrict__ b2, const int* __restrict__ task_id,
    const int* __restrict__ action, float* __restrict__ out) {
  int wid  = (blockIdx.x * 256 + threadIdx.x) >> 6;   // one wave per row
  int lane = threadIdx.x & 63;
  int row  = wid;
  if (row >= B_N) return;
  int t = task_id[row], act = action[row];

  const ushort8v hv8 = *(const ushort8v*)((const unsigned short*)hbuf + (size_t)row * DH + lane * 8);
  float hv[8];
#pragma unroll
  for (int i = 0; i < 8; ++i) hv[i] = bf2f(hv8[i]);

  const float* w2 = W2T + (size_t)t * NACT * DIN;
  float logits[NACT];
#pragma unroll
  for (int j = 0; j < NACT; ++j) {
    const float* wr = w2 + j * DIN + lane * 8;
    float4v w0 = *(const float4v*)wr;
    float4v w1 = *(const float4v*)(wr + 4);
    float p = 0.0f;
#pragma unroll
    for (int i = 0; i < 4; ++i) { p += hv[i] * w0[i]; p += hv[4 + i] * w1[i]; }
#pragma unroll
    for (int s = 32; s > 0; s >>= 1) p += __shfl_xor(p, s);
    logits[j] = p + b2[t * NACT + j];
  }

  float m = -1e30f;
#pragma unroll
  for (int j = 0; j < NACT; ++j) m = fmaxf(m, logits[j]);
  float s1 = 0.0f, s2 = 0.0f, la = 0.0f;
#pragma unroll
  for (int j = 0; j < NACT; ++j) {
    float e = __expf(logits[j] - m);
    s1 += e; s2 += e * logits[j];
    la = (j == act) ? logits[j] : la;
  }
  float logZ = __logf(s1);
  float lp  = la - m - logZ;
  float ent = (m + logZ) - s2 / s1;
  if (lane == 0) {
    out[row * 2 + 0] = lp;
    out[row * 2 + 1] = ent;
  }
}

// ----------------------------------------------------------------------------
extern "C" void kernel_launch(void* const* d_in, const int* in_sizes, int n_in,
                              void* d_out, int out_size, void* d_ws, size_t ws_size,
                              hipStream_t stream) {
  const float* x       = (const float*)d_in[0];
  const int*   task_id = (const int*)d_in[1];
  const int*   action  = (const int*)d_in[2];
  const float* W1      = (const float*)d_in[3];
  const float* b1      = (const float*)d_in[4];
  const float* W2      = (const float*)d_in[5];
  const float* b2      = (const float*)d_in[6];
  float* out = (float*)d_out;

  char* ws = (char*)d_ws;
  int* cnt     = (int*)ws;            // 16
  int* off     = cnt + 16;            // 16
  int* tl_task = off + 16;            // 160
  int* tl_row0 = tl_task + MAXTILE;   // 160
  int* tl_cnt  = tl_row0 + MAXTILE;   // 160
  int* ntile   = tl_cnt + MAXTILE;    // 1
  int* rowidx  = (int*)(ws + 4096);   // 8192 ints -> ends 36864
  short* W1T   = (short*)(ws + 36864);                       // 8388608 B
  float* W2T   = (float*)(ws + 36864 + 8388608);             // 589824 B
  short* hbuf  = (short*)(ws + 36864 + 8388608 + 589824);    // 8388608 B

  k_hist<<<1, 1024, 0, stream>>>(task_id, cnt, off, tl_task, tl_row0, tl_cnt, ntile, rowidx);
  k_tw1<<<dim3(16, 16, 16), 256, 0, stream>>>(W1, W1T);
  k_tw2<<<NTASK, 256, 0, stream>>>(W2, W2T);
  k_gemm1<<<288, 256, 0, stream>>>(x, b1, W1T, rowidx, tl_task, tl_row0, tl_cnt, ntile, hbuf);
  k_head<<<2048, 256, 0, stream>>>(hbuf, W2T, b2, task_id, action, out);
}

// Round 2
// 65.250 us; speedup vs baseline: 1.2395x; 1.2395x over previous
//
#include <hip/hip_runtime.h>
#include <hip/hip_bf16.h>

#define B_N   8192
#define DIN   512
#define DH    512
#define NACT  18
#define NTASK 16
#define BM    64
#define BK    64
#define GBN   128
#define MAXTILE 160

typedef __attribute__((ext_vector_type(8))) short  short8v;
typedef __attribute__((ext_vector_type(8))) unsigned short ushort8v;
typedef __attribute__((ext_vector_type(4))) float  float4v;

typedef const __attribute__((address_space(1))) void* gas_ptr;
typedef __attribute__((address_space(3))) void* las_ptr;

__device__ __forceinline__ unsigned short f2bf(float f) {
  union { float f; unsigned int u; } c; c.f = f;
  unsigned int u = c.u;
  u += 0x7fffu + ((u >> 16) & 1u);   // RNE
  return (unsigned short)(u >> 16);
}
__device__ __forceinline__ float bf2f(unsigned short u) {
  union { unsigned int u; float f; } c; c.u = ((unsigned int)u) << 16;
  return c.f;
}

// ---------------------------------------------------------------- histogram + sort
__global__ __launch_bounds__(1024) void k_hist(
    const int* __restrict__ task_id,
    int* __restrict__ tl_task, int* __restrict__ tl_row0, int* __restrict__ tl_cnt,
    int* __restrict__ ntile, int* __restrict__ rowidx) {
  __shared__ int s_cnt[NTASK];
  __shared__ int s_cur[NTASK];
  int tid = threadIdx.x;
  if (tid < NTASK) s_cnt[tid] = 0;
  __syncthreads();
  for (int i = tid; i < B_N; i += 1024) atomicAdd(&s_cnt[task_id[i]], 1);
  __syncthreads();
  if (tid == 0) {
    int acc = 0, nt = 0;
    for (int t = 0; t < NTASK; ++t) {
      int c = s_cnt[t];
      s_cur[t] = acc;
      for (int r = 0; r < c; r += BM) {
        tl_task[nt] = t; tl_row0[nt] = acc + r;
        tl_cnt[nt] = (c - r < BM) ? (c - r) : BM;
        ++nt;
      }
      acc += c;
    }
    *ntile = nt;
  }
  __syncthreads();
  for (int i = tid; i < B_N; i += 1024) {
    int t = task_id[i];
    int pos = atomicAdd(&s_cur[t], 1);
    rowidx[pos] = i;
  }
}

// ------------------------------------------- gather rows into sorted order + cast bf16
__global__ __launch_bounds__(256) void k_prep(const float* __restrict__ x,
                                              const int* __restrict__ rowidx,
                                              short* __restrict__ xs) {
  int wave = threadIdx.x >> 6, lane = threadIdx.x & 63;
  int srow = blockIdx.x * 4 + wave;          // 2048 blocks -> 8192 rows
  int orig = rowidx[srow];
  const float4v* src = (const float4v*)(x + (size_t)orig * DIN + lane * 8);
  float4v v0 = src[0], v1 = src[1];
  ushort8v o;
#pragma unroll
  for (int i = 0; i < 4; ++i) { o[i] = f2bf(v0[i]); o[4 + i] = f2bf(v1[i]); }
  *(ushort8v*)(xs + (size_t)srow * DIN + lane * 8) = o;
}

// --------------------------------------------- W1 [t][k][n] f32 -> W1T [t][n][k] bf16
__global__ __launch_bounds__(256) void k_tw1(const float* __restrict__ W1,
                                             short* __restrict__ W1T) {
  int nb = blockIdx.x, kb = blockIdx.y, t = blockIdx.z;   // (8,8,16)
  __shared__ short lds[64][72];
  int tid = threadIdx.x;
  int r   = tid >> 2;            // k-row 0..63
  int c16 = (tid & 3) << 4;      // n-col 0,16,32,48
  const float* src = W1 + ((size_t)t * DIN + (size_t)(kb * 64 + r)) * DH + nb * 64 + c16;
#pragma unroll
  for (int p = 0; p < 4; ++p) {
    float4v v = *(const float4v*)(src + p * 4);
#pragma unroll
    for (int i = 0; i < 4; ++i) lds[c16 + p * 4 + i][r] = (short)f2bf(v[i]);
  }
  __syncthreads();
  int n = tid >> 2, k16 = (tid & 3) << 4;
  short* dst = W1T + ((size_t)t * DH + nb * 64 + n) * DIN + kb * 64 + k16;
  *(ushort8v*)dst       = *(ushort8v*)&lds[n][k16];
  *(ushort8v*)(dst + 8) = *(ushort8v*)&lds[n][k16 + 8];
}

// --------------------------------------------- W2 [t][k][j] f32 -> W2T [t][j][k] f32
__global__ __launch_bounds__(256) void k_tw2(const float* __restrict__ W2,
                                             float* __restrict__ W2T) {
  int t = blockIdx.x;
  __shared__ float lds[DIN * NACT];   // 36 KB
  for (int i = threadIdx.x; i < DIN * NACT; i += 256)
    lds[i] = W2[(size_t)t * DIN * NACT + i];
  __syncthreads();
  for (int o = threadIdx.x; o < DIN * NACT; o += 256) {
    int j = o >> 9, k = o & 511;
    W2T[(size_t)t * NACT * DIN + o] = lds[k * NACT + j];
  }
}

// ---------------------------------------------------------------- grouped GEMM1
// hs[srow] = relu(xs[srow] @ W1[task] + b1[task])  (sorted order, bf16)
__global__ __launch_bounds__(256) void k_gemm1(
    const short* __restrict__ xs, const float* __restrict__ b1,
    const short* __restrict__ W1T,
    const int* __restrict__ tl_task, const int* __restrict__ tl_row0,
    const int* __restrict__ tl_cnt, const int* __restrict__ ntile,
    short* __restrict__ hs) {
  __shared__ __align__(16) short sA[BM * BK];     // 8 KB
  __shared__ __align__(16) short sB[GBN * BK];    // 16 KB
  int nt = *ntile;
  int ti = blockIdx.x >> 2;
  if (ti >= nt) return;
  int n0 = (blockIdx.x & 3) * GBN;
  int task = tl_task[ti], row0 = tl_row0[ti], mcnt = tl_cnt[ti];
  int tid = threadIdx.x, lane = tid & 63, wave = tid >> 6;
  int wm = wave >> 1, wn = wave & 1;

  float4v acc[2][4];
#pragma unroll
  for (int i = 0; i < 2; ++i)
#pragma unroll
    for (int j = 0; j < 4; ++j) acc[i][j] = (float4v)0.0f;

  const short* Abase = xs + (size_t)row0 * DIN;
  const short* Bbase = W1T + ((size_t)task * DH + n0) * DIN;

  for (int k0 = 0; k0 < DIN; k0 += BK) {
    // stage A: 64 rows x 64 k bf16 = 512 x 16B chunks; XOR-swizzled global source,
    // linear LDS dest (wave-uniform base + lane*16).
#pragma unroll
    for (int it = 0; it < 2; ++it) {
      int ch = it * 256 + tid;
      int row = ch >> 3, cc = ch & 7;
      int sc = cc ^ (row & 7);
      __builtin_amdgcn_global_load_lds(
          (gas_ptr)(const void*)(Abase + (size_t)row * DIN + k0 + sc * 8),
          (las_ptr)(void*)(sA + ch * 8), 16, 0, 0);
    }
    // stage B: 128 n-rows x 64 k = 1024 chunks
#pragma unroll
    for (int it = 0; it < 4; ++it) {
      int ch = it * 256 + tid;
      int row = ch >> 3, cc = ch & 7;
      int sc = cc ^ (row & 7);
      __builtin_amdgcn_global_load_lds(
          (gas_ptr)(const void*)(Bbase + (size_t)row * DIN + k0 + sc * 8),
          (las_ptr)(void*)(sB + ch * 8), 16, 0, 0);
    }
    asm volatile("s_waitcnt vmcnt(0)" ::: "memory");
    __syncthreads();

#pragma unroll
    for (int ks = 0; ks < 2; ++ks) {
      short8v a[2], b[4];
#pragma unroll
      for (int fm = 0; fm < 2; ++fm) {
        int r = wm * 32 + fm * 16 + (lane & 15);
        int c = (ks * 4 + (lane >> 4)) ^ (r & 7);
        a[fm] = *(const short8v*)(sA + r * BK + c * 8);
      }
#pragma unroll
      for (int fn = 0; fn < 4; ++fn) {
        int r = wn * 64 + fn * 16 + (lane & 15);
        int c = (ks * 4 + (lane >> 4)) ^ (r & 7);
        b[fn] = *(const short8v*)(sB + r * BK + c * 8);
      }
#pragma unroll
      for (int fm = 0; fm < 2; ++fm)
#pragma unroll
        for (int fn = 0; fn < 4; ++fn)
          acc[fm][fn] = __builtin_amdgcn_mfma_f32_16x16x32_bf16(a[fm], b[fn], acc[fm][fn], 0, 0, 0);
    }
    __syncthreads();
  }

  // epilogue: +b1, relu, bf16, store sorted-contiguous
  int cl = lane & 15, rb = (lane >> 4) << 2;
#pragma unroll
  for (int fn = 0; fn < 4; ++fn) {
    int col = n0 + wn * 64 + fn * 16 + cl;
    float bias = b1[task * DH + col];
#pragma unroll
    for (int fm = 0; fm < 2; ++fm) {
#pragma unroll
      for (int r = 0; r < 4; ++r) {
        int m = wm * 32 + fm * 16 + rb + r;
        if (m < mcnt) {
          float v = fmaxf(acc[fm][fn][r] + bias, 0.0f);
          hs[(size_t)(row0 + m) * DH + col] = (short)f2bf(v);
        }
      }
    }
  }
}

// ---------------------------------------------------------------- head: layer2 + log_softmax
__global__ __launch_bounds__(256) void k_head(
    const short* __restrict__ hs, const float* __restrict__ W2T,
    const float* __restrict__ b2, const int* __restrict__ task_id,
    const int* __restrict__ action, const int* __restrict__ rowidx,
    float* __restrict__ out) {
  int wid  = (blockIdx.x * 256 + threadIdx.x) >> 6;   // sorted row, one wave per row
  int lane = threadIdx.x & 63;
  int orig = rowidx[wid];
  int t = task_id[orig], act = action[orig];

  const ushort8v hv8 = *(const ushort8v*)((const unsigned short*)hs + (size_t)wid * DH + lane * 8);
  float hv[8];
#pragma unroll
  for (int i = 0; i < 8; ++i) hv[i] = bf2f(hv8[i]);

  const float* w2 = W2T + (size_t)t * NACT * DIN;
  float logits[NACT];
#pragma unroll
  for (int j = 0; j < NACT; ++j) {
    const float* wr = w2 + j * DIN + lane * 8;
    float4v w0 = *(const float4v*)wr;
    float4v w1 = *(const float4v*)(wr + 4);
    float p = 0.0f;
#pragma unroll
    for (int i = 0; i < 4; ++i) { p += hv[i] * w0[i]; p += hv[4 + i] * w1[i]; }
#pragma unroll
    for (int s = 32; s > 0; s >>= 1) p += __shfl_xor(p, s);
    logits[j] = p + b2[t * NACT + j];
  }

  float m = -1e30f;
#pragma unroll
  for (int j = 0; j < NACT; ++j) m = fmaxf(m, logits[j]);
  float s1 = 0.0f, s2 = 0.0f, la = 0.0f;
#pragma unroll
  for (int j = 0; j < NACT; ++j) {
    float e = __expf(logits[j] - m);
    s1 += e; s2 += e * logits[j];
    la = (j == act) ? logits[j] : la;
  }
  float logZ = __logf(s1);
  float lp  = la - m - logZ;
  float ent = (m + logZ) - s2 / s1;
  if (lane == 0) {
    out[orig * 2 + 0] = lp;
    out[orig * 2 + 1] = ent;
  }
}

// ----------------------------------------------------------------------------
extern "C" void kernel_launch(void* const* d_in, const int* in_sizes, int n_in,
                              void* d_out, int out_size, void* d_ws, size_t ws_size,
                              hipStream_t stream) {
  const float* x       = (const float*)d_in[0];
  const int*   task_id = (const int*)d_in[1];
  const int*   action  = (const int*)d_in[2];
  const float* W1      = (const float*)d_in[3];
  const float* b1      = (const float*)d_in[4];
  const float* W2      = (const float*)d_in[5];
  const float* b2      = (const float*)d_in[6];
  float* out = (float*)d_out;

  char* ws = (char*)d_ws;
  int* tl_task = (int*)ws;                 // 160
  int* tl_row0 = tl_task + MAXTILE;        // 160
  int* tl_cnt  = tl_row0 + MAXTILE;        // 160
  int* ntile   = tl_cnt + MAXTILE;         // 1
  int* rowidx  = (int*)(ws + 4096);        // 8192 ints  -> ends 36864
  size_t off = 36864;
  short* xs  = (short*)(ws + off);  off += (size_t)(B_N + BM) * DIN * 2;  // 8.45 MB (+slack rows)
  short* W1T = (short*)(ws + off);  off += (size_t)NTASK * DH * DIN * 2;  // 8.39 MB
  float* W2T = (float*)(ws + off);  off += (size_t)NTASK * NACT * DIN * 4;// 0.59 MB
  short* hs  = (short*)(ws + off);                                        // 8.39 MB

  k_hist<<<1, 1024, 0, stream>>>(task_id, tl_task, tl_row0, tl_cnt, ntile, rowidx);
  k_tw1<<<dim3(8, 8, 16), 256, 0, stream>>>(W1, W1T);
  k_tw2<<<NTASK, 256, 0, stream>>>(W2, W2T);
  k_prep<<<2048, 256, 0, stream>>>(x, rowidx, xs);
  k_gemm1<<<576, 256, 0, stream>>>(xs, b1, W1T, tl_task, tl_row0, tl_cnt, ntile, hs);
  k_head<<<2048, 256, 0, stream>>>(hs, W2T, b2, task_id, action, rowidx, out);
}